// Round 5
// baseline (244.293 us; speedup 1.0000x reference)
//
#include <hip/hip_runtime.h>

#define BATCH 65536
#define DIM 512
#define NCLS 100
#define ALPHA 0.5f

#define CAP 1024            // per-class slot capacity (max count ~780 for B=65536,C=100)
#define SORT_RPB 256        // rows per block in sort_kernel (1 row/thread)
#define SORT_THREADS 256
#define CHUNKS 16           // blocks per class in delta_kernel
#define CBLOCK 256          // threads per block (4 waves)
#define SLOTS (CHUNKS * (CBLOCK / 64))   // 64 wave-slots per class

// workspace layout
#define WS_COUNTS_OFF 0                   // 128 ints
#define WS_DONE_OFF   512                 // 128 ints (per-class completion counters)
#define WS_ORDER_OFF  1024                // NCLS*CAP ints
#define WS_AUX_OFF    (1024 + NCLS * CAP * 4)
#define WS_PART_BYTES (CHUNKS * NCLS * DIM * 4)

// ---------------------------------------------------------------------------
// Kernel A: fused label-extract + counting-sort with LDS histogram.
// Label via exact dot-product: label[b] = sum_c onehot[b][c] * c.
// Only 100 global atomics per block (base-offset claim).
// ---------------------------------------------------------------------------
__global__ void __launch_bounds__(SORT_THREADS)
sort_kernel(const float* __restrict__ onehot,
            int* __restrict__ counts,      // [NCLS], pre-zeroed
            int* __restrict__ order) {     // [NCLS][CAP]
    __shared__ int lhist[NCLS];
    __shared__ int lbase[NCLS];
    __shared__ short llab[SORT_RPB];
    __shared__ short lrank[SORT_RPB];

    const int t = threadIdx.x;
    const int r0 = blockIdx.x * SORT_RPB;

    for (int c = t; c < NCLS; c += SORT_THREADS) lhist[c] = 0;
    __syncthreads();

    const float4* oh4 = reinterpret_cast<const float4*>(onehot);
    {
        const int b = r0 + t;
        float lab = 0.0f;
#pragma unroll
        for (int j = 0; j < NCLS / 4; ++j) {
            const float4 v = oh4[b * (NCLS / 4) + j];
            lab += v.x * (float)(4 * j)
                 + v.y * (float)(4 * j + 1)
                 + v.z * (float)(4 * j + 2)
                 + v.w * (float)(4 * j + 3);
        }
        const int c = (int)(lab + 0.5f);
        llab[t] = (short)c;
        lrank[t] = (short)atomicAdd(&lhist[c], 1);
    }
    __syncthreads();

    for (int c = t; c < NCLS; c += SORT_THREADS)
        lbase[c] = atomicAdd(&counts[c], lhist[c]);
    __syncthreads();

    {
        const int c = llab[t];
        order[c * CAP + lbase[c] + lrank[t]] = r0 + t;
    }
}

// ---------------------------------------------------------------------------
// Kernel B: fused squared-distance + per-class feature-sum + per-class
// finalize (last-block-done). grid = (CHUNKS, NCLS), block = 256 (4 waves).
// Each wave handles rows of ONE class; lane owns dims [lane*8, lane*8+8).
// Hot loop unrolled x4 (9 loads in flight). Register accumulation only.
// ---------------------------------------------------------------------------
__global__ void __launch_bounds__(CBLOCK)
delta_kernel(const float* __restrict__ features,
             const float* __restrict__ centers,
             const int* __restrict__ order,
             const int* __restrict__ counts,
             float* __restrict__ aux,       // part [CHUNKS][NCLS][DIM] or sumf [NCLS][DIM]
             float* __restrict__ result,    // [BATCH], each row written once
             int* __restrict__ done,        // [NCLS], pre-zeroed
             float* __restrict__ new_centers,
             const int use_part) {
    __shared__ float red[4][DIM];          // 8 KB
    __shared__ int lastflag;

    const int c = blockIdx.y;
    const int cnt = counts[c];
    const int lane = threadIdx.x & 63;
    const int wave = threadIdx.x >> 6;
    const int slot = blockIdx.x * (CBLOCK / 64) + wave;   // 0..SLOTS-1
    const int d = lane * 8;

    const float4 c0 = *reinterpret_cast<const float4*>(&centers[c * DIM + d]);
    const float4 c1 = *reinterpret_cast<const float4*>(&centers[c * DIM + d + 4]);
    float4 sA = make_float4(0.f, 0.f, 0.f, 0.f);
    float4 sB = make_float4(0.f, 0.f, 0.f, 0.f);

    const int* ord = &order[c * CAP];
    int i = slot;
    for (; i + 3 * SLOTS < cnt; i += 4 * SLOTS) {
        const int b0 = ord[i];
        const int b1 = ord[i + SLOTS];
        const int b2 = ord[i + 2 * SLOTS];
        const int b3 = ord[i + 3 * SLOTS];
        const float4 f00 = *reinterpret_cast<const float4*>(&features[b0 * DIM + d]);
        const float4 f01 = *reinterpret_cast<const float4*>(&features[b0 * DIM + d + 4]);
        const float4 f10 = *reinterpret_cast<const float4*>(&features[b1 * DIM + d]);
        const float4 f11 = *reinterpret_cast<const float4*>(&features[b1 * DIM + d + 4]);
        const float4 f20 = *reinterpret_cast<const float4*>(&features[b2 * DIM + d]);
        const float4 f21 = *reinterpret_cast<const float4*>(&features[b2 * DIM + d + 4]);
        const float4 f30 = *reinterpret_cast<const float4*>(&features[b3 * DIM + d]);
        const float4 f31 = *reinterpret_cast<const float4*>(&features[b3 * DIM + d + 4]);

        sA.x += f00.x + f10.x + f20.x + f30.x;
        sA.y += f00.y + f10.y + f20.y + f30.y;
        sA.z += f00.z + f10.z + f20.z + f30.z;
        sA.w += f00.w + f10.w + f20.w + f30.w;
        sB.x += f01.x + f11.x + f21.x + f31.x;
        sB.y += f01.y + f11.y + f21.y + f31.y;
        sB.z += f01.z + f11.z + f21.z + f31.z;
        sB.w += f01.w + f11.w + f21.w + f31.w;

        float dx, dy, dz, dw;
        dx = f00.x - c0.x; dy = f00.y - c0.y; dz = f00.z - c0.z; dw = f00.w - c0.w;
        float sq0 = dx * dx + dy * dy + dz * dz + dw * dw;
        dx = f01.x - c1.x; dy = f01.y - c1.y; dz = f01.z - c1.z; dw = f01.w - c1.w;
        sq0 += dx * dx + dy * dy + dz * dz + dw * dw;
        dx = f10.x - c0.x; dy = f10.y - c0.y; dz = f10.z - c0.z; dw = f10.w - c0.w;
        float sq1 = dx * dx + dy * dy + dz * dz + dw * dw;
        dx = f11.x - c1.x; dy = f11.y - c1.y; dz = f11.z - c1.z; dw = f11.w - c1.w;
        sq1 += dx * dx + dy * dy + dz * dz + dw * dw;
        dx = f20.x - c0.x; dy = f20.y - c0.y; dz = f20.z - c0.z; dw = f20.w - c0.w;
        float sq2 = dx * dx + dy * dy + dz * dz + dw * dw;
        dx = f21.x - c1.x; dy = f21.y - c1.y; dz = f21.z - c1.z; dw = f21.w - c1.w;
        sq2 += dx * dx + dy * dy + dz * dz + dw * dw;
        dx = f30.x - c0.x; dy = f30.y - c0.y; dz = f30.z - c0.z; dw = f30.w - c0.w;
        float sq3 = dx * dx + dy * dy + dz * dz + dw * dw;
        dx = f31.x - c1.x; dy = f31.y - c1.y; dz = f31.z - c1.z; dw = f31.w - c1.w;
        sq3 += dx * dx + dy * dy + dz * dz + dw * dw;

#pragma unroll
        for (int m = 32; m >= 1; m >>= 1) {
            sq0 += __shfl_xor(sq0, m);
            sq1 += __shfl_xor(sq1, m);
            sq2 += __shfl_xor(sq2, m);
            sq3 += __shfl_xor(sq3, m);
        }
        if (lane == 0) {
            result[b0] = sq0;
            result[b1] = sq1;
            result[b2] = sq2;
            result[b3] = sq3;
        }
    }
    for (; i < cnt; i += SLOTS) {
        const int b = ord[i];
        const float4 f0 = *reinterpret_cast<const float4*>(&features[b * DIM + d]);
        const float4 f1 = *reinterpret_cast<const float4*>(&features[b * DIM + d + 4]);
        sA.x += f0.x; sA.y += f0.y; sA.z += f0.z; sA.w += f0.w;
        sB.x += f1.x; sB.y += f1.y; sB.z += f1.z; sB.w += f1.w;
        float dx, dy, dz, dw;
        dx = f0.x - c0.x; dy = f0.y - c0.y; dz = f0.z - c0.z; dw = f0.w - c0.w;
        float sq = dx * dx + dy * dy + dz * dz + dw * dw;
        dx = f1.x - c1.x; dy = f1.y - c1.y; dz = f1.z - c1.z; dw = f1.w - c1.w;
        sq += dx * dx + dy * dy + dz * dz + dw * dw;
#pragma unroll
        for (int m = 32; m >= 1; m >>= 1) sq += __shfl_xor(sq, m);
        if (lane == 0) result[b] = sq;
    }

    // cross-wave reduction in LDS
    float* r = &red[wave][d];
    r[0] = sA.x; r[1] = sA.y; r[2] = sA.z; r[3] = sA.w;
    r[4] = sB.x; r[5] = sB.y; r[6] = sB.z; r[7] = sB.w;
    __syncthreads();

    const int t = threadIdx.x;
    if (use_part) {
        // one streaming 2KB partial write per block, then last-block finalize
        float* dst = &aux[(blockIdx.x * NCLS + c) * DIM];
#pragma unroll
        for (int k = 0; k < DIM / CBLOCK; ++k) {
            const int dd = k * CBLOCK + t;
            dst[dd] = red[0][dd] + red[1][dd] + red[2][dd] + red[3][dd];
        }
        __threadfence();                    // make partial visible device-wide
        if (t == 0)
            lastflag = (atomicAdd(&done[c], 1) == CHUNKS - 1) ? 1 : 0;
        __syncthreads();
        if (lastflag) {
            __threadfence();                // acquire: see all partials
            const float cntf = (float)cnt;
#pragma unroll
            for (int k = 0; k < DIM / CBLOCK; ++k) {
                const int dd = k * CBLOCK + t;
                float s = 0.0f;
#pragma unroll
                for (int ch = 0; ch < CHUNKS; ++ch)
                    s += aux[(ch * NCLS + c) * DIM + dd];
                const float ctr = centers[c * DIM + dd];
                const float delta = (cntf * ctr - s) / (cntf + 1.0f);
                new_centers[c * DIM + dd] = ctr - ALPHA * delta;
            }
        }
    } else {
#pragma unroll
        for (int k = 0; k < DIM / CBLOCK; ++k) {
            const int dd = k * CBLOCK + t;
            const float s = red[0][dd] + red[1][dd] + red[2][dd] + red[3][dd];
            unsafeAtomicAdd(&aux[c * DIM + dd], s);
        }
    }
}

// ---------------------------------------------------------------------------
// Kernel C (fallback only): new_centers = centers - ALPHA*(cnt*ctr - sumf)/(cnt+1)
// ---------------------------------------------------------------------------
__global__ void finalize_kernel(const float* __restrict__ centers,
                                const float* __restrict__ aux,
                                const int* __restrict__ counts,
                                float* __restrict__ new_centers) {
    const int idx = blockIdx.x * blockDim.x + threadIdx.x;
    if (idx >= NCLS * DIM) return;
    const float s = aux[idx];
    const int c = idx >> 9;                 // / DIM
    const float cntf = (float)counts[c];
    const float ctr = centers[idx];
    const float delta = (cntf * ctr - s) / (cntf + 1.0f);
    new_centers[idx] = ctr - ALPHA * delta;
}

extern "C" void kernel_launch(void* const* d_in, const int* in_sizes, int n_in,
                              void* d_out, int out_size, void* d_ws, size_t ws_size,
                              hipStream_t stream) {
    const float* features = (const float*)d_in[0];   // [65536, 512]
    const float* onehot   = (const float*)d_in[1];   // [65536, 100]
    const float* centers  = (const float*)d_in[2];   // [100, 512]

    float* result      = (float*)d_out;              // [65536]
    float* new_centers = (float*)d_out + BATCH;      // [100*512]

    char* ws = (char*)d_ws;
    int*   counts = (int*)(ws + WS_COUNTS_OFF);      // 128 ints
    int*   done   = (int*)(ws + WS_DONE_OFF);        // 128 ints
    int*   order  = (int*)(ws + WS_ORDER_OFF);       // NCLS*CAP ints
    float* aux    = (float*)(ws + WS_AUX_OFF);       // part or sumf

    const int use_part = (ws_size >= (size_t)WS_AUX_OFF + WS_PART_BYTES) ? 1 : 0;

    // zero counts + done in one tiny memset
    hipMemsetAsync(ws, 0, 1024, stream);
    if (!use_part)
        hipMemsetAsync(aux, 0, NCLS * DIM * sizeof(float), stream);

    sort_kernel<<<BATCH / SORT_RPB, SORT_THREADS, 0, stream>>>(onehot, counts, order);

    dim3 grid(CHUNKS, NCLS);
    delta_kernel<<<grid, CBLOCK, 0, stream>>>(features, centers, order, counts,
                                              aux, result, done, new_centers, use_part);

    if (!use_part)
        finalize_kernel<<<(NCLS * DIM + 255) / 256, 256, 0, stream>>>(centers, aux, counts, new_centers);
}

// Round 6
// 46.140 us; speedup vs baseline: 5.2946x; 5.2946x over previous
//
#include <hip/hip_runtime.h>

#define BATCH 65536
#define DIM 512
#define NCLS 100
#define ALPHA 0.5f

#define CAP 1024            // per-class slot capacity (max count ~780 for B=65536,C=100)
#define SORT_RPB 512        // rows per block in sort_kernel
#define SORT_THREADS 256
#define CHUNKS 32           // blocks per class in delta_kernel
#define CBLOCK 256          // threads per block (4 waves)
#define SLOTS (CHUNKS * (CBLOCK / 64))   // 128 wave-slots per class

// workspace layout
#define WS_COUNTS_OFF 0
#define WS_ORDER_OFF  512
#define WS_AUX_OFF    (512 + NCLS * CAP * 4)          // part (6.5MB) or sumf (200KB)
#define WS_PART_BYTES (CHUNKS * NCLS * DIM * 4)

// ---------------------------------------------------------------------------
// Kernel A: fused label-extract + counting-sort with LDS histogram.
// Label via exact dot-product: label[b] = sum_c onehot[b][c] * c.
// Only 100 global atomics per block (base-offset claim).
// ---------------------------------------------------------------------------
__global__ void __launch_bounds__(SORT_THREADS)
sort_kernel(const float* __restrict__ onehot,
            int* __restrict__ counts,      // [NCLS], pre-zeroed
            int* __restrict__ order) {     // [NCLS][CAP]
    __shared__ int lhist[NCLS];
    __shared__ int lbase[NCLS];
    __shared__ short llab[SORT_RPB];
    __shared__ short lrank[SORT_RPB];

    const int t = threadIdx.x;
    const int r0 = blockIdx.x * SORT_RPB;

    for (int c = t; c < NCLS; c += SORT_THREADS) lhist[c] = 0;
    __syncthreads();

    const float4* oh4 = reinterpret_cast<const float4*>(onehot);
#pragma unroll
    for (int rr = 0; rr < SORT_RPB / SORT_THREADS; ++rr) {
        const int r = rr * SORT_THREADS + t;
        const int b = r0 + r;
        float lab = 0.0f;
#pragma unroll
        for (int j = 0; j < NCLS / 4; ++j) {
            const float4 v = oh4[b * (NCLS / 4) + j];
            lab += v.x * (float)(4 * j)
                 + v.y * (float)(4 * j + 1)
                 + v.z * (float)(4 * j + 2)
                 + v.w * (float)(4 * j + 3);
        }
        const int c = (int)(lab + 0.5f);
        llab[r] = (short)c;
        lrank[r] = (short)atomicAdd(&lhist[c], 1);
    }
    __syncthreads();

    for (int c = t; c < NCLS; c += SORT_THREADS)
        lbase[c] = atomicAdd(&counts[c], lhist[c]);
    __syncthreads();

#pragma unroll
    for (int rr = 0; rr < SORT_RPB / SORT_THREADS; ++rr) {
        const int r = rr * SORT_THREADS + t;
        const int c = llab[r];
        order[c * CAP + lbase[c] + lrank[r]] = r0 + r;
    }
}

// ---------------------------------------------------------------------------
// Kernel B: fused squared-distance + per-class feature-sum.
// grid = (CHUNKS, NCLS), block = 256 (4 waves), each wave handles rows of ONE
// class; lane owns dims [lane*8, lane*8+8). Register accumulation in the hot
// loop (unrolled x2 for MLP), LDS cross-wave reduce at block end, then ONE
// non-atomic 2KB streaming partial write per block (use_part mode).
// NO device-scope fences here: a per-block __threadfence() on CDNA4 is a full
// per-XCD L2 writeback (non-coherent L2s) and cost 5x in round 5.
// ---------------------------------------------------------------------------
__global__ void __launch_bounds__(CBLOCK)
delta_kernel(const float* __restrict__ features,
             const float* __restrict__ centers,
             const int* __restrict__ order,
             const int* __restrict__ counts,
             float* __restrict__ aux,       // part [CHUNKS][NCLS][DIM] or sumf [NCLS][DIM]
             float* __restrict__ result,    // [BATCH], each row written once
             const int use_part) {
    __shared__ float red[4][DIM];          // 8 KB

    const int c = blockIdx.y;
    const int cnt = counts[c];
    const int lane = threadIdx.x & 63;
    const int wave = threadIdx.x >> 6;
    const int slot = blockIdx.x * (CBLOCK / 64) + wave;   // 0..SLOTS-1
    const int d = lane * 8;

    const float4 c0 = *reinterpret_cast<const float4*>(&centers[c * DIM + d]);
    const float4 c1 = *reinterpret_cast<const float4*>(&centers[c * DIM + d + 4]);
    float4 sA = make_float4(0.f, 0.f, 0.f, 0.f);
    float4 sB = make_float4(0.f, 0.f, 0.f, 0.f);

    const int* ord = &order[c * CAP];
    int i = slot;
    for (; i + SLOTS < cnt; i += 2 * SLOTS) {
        const int b0 = ord[i];
        const int b1 = ord[i + SLOTS];
        const float4 f00 = *reinterpret_cast<const float4*>(&features[b0 * DIM + d]);
        const float4 f01 = *reinterpret_cast<const float4*>(&features[b0 * DIM + d + 4]);
        const float4 f10 = *reinterpret_cast<const float4*>(&features[b1 * DIM + d]);
        const float4 f11 = *reinterpret_cast<const float4*>(&features[b1 * DIM + d + 4]);

        sA.x += f00.x + f10.x; sA.y += f00.y + f10.y;
        sA.z += f00.z + f10.z; sA.w += f00.w + f10.w;
        sB.x += f01.x + f11.x; sB.y += f01.y + f11.y;
        sB.z += f01.z + f11.z; sB.w += f01.w + f11.w;

        float dx, dy, dz, dw;
        dx = f00.x - c0.x; dy = f00.y - c0.y; dz = f00.z - c0.z; dw = f00.w - c0.w;
        float sq0 = dx * dx + dy * dy + dz * dz + dw * dw;
        dx = f01.x - c1.x; dy = f01.y - c1.y; dz = f01.z - c1.z; dw = f01.w - c1.w;
        sq0 += dx * dx + dy * dy + dz * dz + dw * dw;
        dx = f10.x - c0.x; dy = f10.y - c0.y; dz = f10.z - c0.z; dw = f10.w - c0.w;
        float sq1 = dx * dx + dy * dy + dz * dz + dw * dw;
        dx = f11.x - c1.x; dy = f11.y - c1.y; dz = f11.z - c1.z; dw = f11.w - c1.w;
        sq1 += dx * dx + dy * dy + dz * dz + dw * dw;

#pragma unroll
        for (int m = 32; m >= 1; m >>= 1) {
            sq0 += __shfl_xor(sq0, m);
            sq1 += __shfl_xor(sq1, m);
        }
        if (lane == 0) {
            result[b0] = sq0;
            result[b1] = sq1;
        }
    }
    if (i < cnt) {
        const int b = ord[i];
        const float4 f0 = *reinterpret_cast<const float4*>(&features[b * DIM + d]);
        const float4 f1 = *reinterpret_cast<const float4*>(&features[b * DIM + d + 4]);
        sA.x += f0.x; sA.y += f0.y; sA.z += f0.z; sA.w += f0.w;
        sB.x += f1.x; sB.y += f1.y; sB.z += f1.z; sB.w += f1.w;
        float dx, dy, dz, dw;
        dx = f0.x - c0.x; dy = f0.y - c0.y; dz = f0.z - c0.z; dw = f0.w - c0.w;
        float sq = dx * dx + dy * dy + dz * dz + dw * dw;
        dx = f1.x - c1.x; dy = f1.y - c1.y; dz = f1.z - c1.z; dw = f1.w - c1.w;
        sq += dx * dx + dy * dy + dz * dz + dw * dw;
#pragma unroll
        for (int m = 32; m >= 1; m >>= 1) sq += __shfl_xor(sq, m);
        if (lane == 0) result[b] = sq;
    }

    // cross-wave reduction in LDS, then one streaming partial write per block
    float* r = &red[wave][d];
    r[0] = sA.x; r[1] = sA.y; r[2] = sA.z; r[3] = sA.w;
    r[4] = sB.x; r[5] = sB.y; r[6] = sB.z; r[7] = sB.w;
    __syncthreads();

    const int t = threadIdx.x;
    if (use_part) {
        float* dst = &aux[(blockIdx.x * NCLS + c) * DIM];
#pragma unroll
        for (int k = 0; k < DIM / CBLOCK; ++k) {
            const int dd = k * CBLOCK + t;
            dst[dd] = red[0][dd] + red[1][dd] + red[2][dd] + red[3][dd];
        }
    } else {
#pragma unroll
        for (int k = 0; k < DIM / CBLOCK; ++k) {
            const int dd = k * CBLOCK + t;
            const float s = red[0][dd] + red[1][dd] + red[2][dd] + red[3][dd];
            unsafeAtomicAdd(&aux[c * DIM + dd], s);
        }
    }
}

// ---------------------------------------------------------------------------
// Kernel C: new_centers = centers - ALPHA * (cnt*center - sumf) / (cnt + 1)
// ---------------------------------------------------------------------------
__global__ void finalize_kernel(const float* __restrict__ centers,
                                const float* __restrict__ aux,
                                const int* __restrict__ counts,
                                float* __restrict__ new_centers,
                                const int use_part) {
    const int idx = blockIdx.x * blockDim.x + threadIdx.x;
    if (idx >= NCLS * DIM) return;
    float s;
    if (use_part) {
        s = 0.0f;
#pragma unroll
        for (int k = 0; k < CHUNKS; ++k) s += aux[k * NCLS * DIM + idx];
    } else {
        s = aux[idx];
    }
    const int c = idx >> 9;                 // / DIM
    const float cntf = (float)counts[c];
    const float ctr = centers[idx];
    const float delta = (cntf * ctr - s) / (cntf + 1.0f);
    new_centers[idx] = ctr - ALPHA * delta;
}

extern "C" void kernel_launch(void* const* d_in, const int* in_sizes, int n_in,
                              void* d_out, int out_size, void* d_ws, size_t ws_size,
                              hipStream_t stream) {
    const float* features = (const float*)d_in[0];   // [65536, 512]
    const float* onehot   = (const float*)d_in[1];   // [65536, 100]
    const float* centers  = (const float*)d_in[2];   // [100, 512]

    float* result      = (float*)d_out;              // [65536]
    float* new_centers = (float*)d_out + BATCH;      // [100*512]

    char* ws = (char*)d_ws;
    int*   counts = (int*)(ws + WS_COUNTS_OFF);      // 128 ints
    int*   order  = (int*)(ws + WS_ORDER_OFF);       // NCLS*CAP ints
    float* aux    = (float*)(ws + WS_AUX_OFF);       // part or sumf

    const int use_part = (ws_size >= (size_t)WS_AUX_OFF + WS_PART_BYTES) ? 1 : 0;

    hipMemsetAsync(counts, 0, 128 * sizeof(int), stream);
    if (!use_part)
        hipMemsetAsync(aux, 0, NCLS * DIM * sizeof(float), stream);

    sort_kernel<<<BATCH / SORT_RPB, SORT_THREADS, 0, stream>>>(onehot, counts, order);

    dim3 grid(CHUNKS, NCLS);
    delta_kernel<<<grid, CBLOCK, 0, stream>>>(features, centers, order, counts, aux, result, use_part);

    finalize_kernel<<<(NCLS * DIM + 255) / 256, 256, 0, stream>>>(centers, aux, counts, new_centers, use_part);
}